// Round 2
// baseline (739.020 us; speedup 1.0000x reference)
//
#include <hip/hip_runtime.h>
#include <math.h>

#define B_   32
#define N_   325
#define L_   12
#define D_   128
#define H_   8
#define DK_  16
#define BN_  (B_*N_)        // 10400
#define ROWS_ (BN_*L_)      // 124800
#define TAB_ 23             // 2*MAX_REL+1
#define BNH_ (BN_*H_)       // 83200
#define OUT_MAIN_ ((size_t)ROWS_ * D_)   // 15,974,400 floats

// ---------------------------------------------------------------------------
// prep: weight-norm all 4 matrices -> transposed fp32 Wt[i][o] = v[o][i]*g[o]/||v[o]||
// extra block zeroes the BN accumulators (ws is poisoned 0xAA before each launch)
// ---------------------------------------------------------------------------
__global__ __launch_bounds__(64)
void prep_kernel(const float* __restrict__ wqv, const float* __restrict__ wqg,
                 const float* __restrict__ wkv, const float* __restrict__ wkg,
                 const float* __restrict__ wvv, const float* __restrict__ wvg,
                 const float* __restrict__ fcv, const float* __restrict__ fcg,
                 float* __restrict__ Wt, float* __restrict__ stats)
{
    const int b = blockIdx.x, t = threadIdx.x;
    if (b == 4*D_) {
        for (int j = t; j < 256; j += 64) stats[j] = 0.f;
        return;
    }
    const int m = b >> 7, o = b & 127;
    const float* v; const float* g;
    if      (m == 0) { v = wqv; g = wqg; }
    else if (m == 1) { v = wkv; g = wkg; }
    else if (m == 2) { v = wvv; g = wvg; }
    else             { v = fcv; g = fcg; }
    float x0 = v[o*D_ + t];
    float x1 = v[o*D_ + t + 64];
    float ss = x0*x0 + x1*x1;
    #pragma unroll
    for (int off = 32; off > 0; off >>= 1) ss += __shfl_down(ss, off, 64);
    ss = __shfl(ss, 0, 64);
    float scale = g[o] / sqrtf(ss);
    float* W = Wt + m*(D_*D_);
    W[t*D_ + o]      = x0*scale;
    W[(t+64)*D_ + o] = x1*scale;
}

// ---------------------------------------------------------------------------
// attention: one block per (b,n). 192 threads (3 waves, one per Q/K/V matrix).
// ---------------------------------------------------------------------------
__global__ __launch_bounds__(192)
void attn_kernel(const float* __restrict__ xq, const float* __restrict__ xk,
                 const float* __restrict__ xv,
                 const float* __restrict__ relk, const float* __restrict__ relv,
                 const float* __restrict__ w1g, const float* __restrict__ w2g,
                 const float* __restrict__ Wt,
                 float* __restrict__ outm, float* __restrict__ attn_out)
{
    __shared__ float sX[3][L_][D_];      // staged inputs
    __shared__ float sQKV[3][L_][D_];    // projected Q,K,V
    __shared__ float sS [H_][L_][L_];
    __shared__ float sS2[H_][L_][L_];
    __shared__ float sRk[TAB_*DK_];
    __shared__ float sRv[TAB_*DK_];
    __shared__ float sW1[H_*H_];
    __shared__ float sW2[H_*H_];

    const int tid = threadIdx.x;
    const int bn  = blockIdx.x;
    const size_t base = (size_t)bn * (L_*D_);

    // stage inputs (float4)
    #pragma unroll
    for (int m = 0; m < 3; ++m) {
        const float* src = (m == 0) ? xq : ((m == 1) ? xk : xv);
        const float4* s4 = (const float4*)(src + base);
        float4* d4 = (float4*)&sX[m][0][0];
        for (int idx = tid; idx < L_*D_/4; idx += 192) d4[idx] = s4[idx];
    }
    for (int idx = tid; idx < TAB_*DK_; idx += 192) {
        sRk[idx] = relk[idx];
        sRv[idx] = relv[idx];
    }
    if (tid < H_*H_) { sW1[tid] = w1g[tid]; sW2[tid] = w2g[tid]; }
    __syncthreads();

    // QKV projection: wave m handles matrix m; lane -> (4 cols, 6 rows)
    {
        const int m    = tid / 64;            // wave-uniform
        const int lane = tid & 63;
        const int oc   = (lane & 31) * 4;
        const int r0   = (lane >> 5) * 6;
        const float* W = Wt + m*(D_*D_) + oc;
        float acc[6][4];
        #pragma unroll
        for (int r = 0; r < 6; ++r) {
            #pragma unroll
            for (int c = 0; c < 4; ++c) acc[r][c] = 0.f;
        }
        for (int i = 0; i < D_; i += 4) {
            float4 w0 = *(const float4*)&W[(i+0)*D_];
            float4 w1 = *(const float4*)&W[(i+1)*D_];
            float4 w2 = *(const float4*)&W[(i+2)*D_];
            float4 w3 = *(const float4*)&W[(i+3)*D_];
            #pragma unroll
            for (int r = 0; r < 6; ++r) {
                float4 x = *(const float4*)&sX[m][r0+r][i];
                acc[r][0] += x.x*w0.x + x.y*w1.x + x.z*w2.x + x.w*w3.x;
                acc[r][1] += x.x*w0.y + x.y*w1.y + x.z*w2.y + x.w*w3.y;
                acc[r][2] += x.x*w0.z + x.y*w1.z + x.z*w2.z + x.w*w3.z;
                acc[r][3] += x.x*w0.w + x.y*w1.w + x.z*w2.w + x.w*w3.w;
            }
        }
        #pragma unroll
        for (int r = 0; r < 6; ++r) {
            sQKV[m][r0+r][oc+0] = acc[r][0];
            sQKV[m][r0+r][oc+1] = acc[r][1];
            sQKV[m][r0+r][oc+2] = acc[r][2];
            sQKV[m][r0+r][oc+3] = acc[r][3];
        }
    }
    __syncthreads();

    // scores: s1+s2 = sum_d Q*(K + relK), scaled 1/sqrt(dk)=0.25
    for (int task = tid; task < H_*L_*L_; task += 192) {
        const int h = task / (L_*L_);
        const int r = task - h*(L_*L_);
        const int q = r / L_;
        const int k = r - q*L_;
        const float* Qp = &sQKV[0][q][h*DK_];
        const float* Kp = &sQKV[1][k][h*DK_];
        const float* Rp = &sRk[(k - q + 11)*DK_];
        float s = 0.f;
        #pragma unroll
        for (int d = 0; d < DK_; ++d) s += Qp[d] * (Kp[d] + Rp[d]);
        sS[h][q][k] = s * 0.25f;
    }
    __syncthreads();

    // w1 cross-head mix -> leaky relu -> softmax over k
    if (tid < H_*L_) {
        const int g = tid / L_;
        const int q = tid - g*L_;
        float vals[L_];
        float mx = -1e30f;
        #pragma unroll
        for (int k = 0; k < L_; ++k) {
            float a = 0.f;
            #pragma unroll
            for (int h = 0; h < H_; ++h) a += sS[h][q][k] * sW1[h*H_ + g];
            a = (a >= 0.f) ? a : 0.2f*a;
            vals[k] = a;
            mx = fmaxf(mx, a);
        }
        float sum = 0.f;
        #pragma unroll
        for (int k = 0; k < L_; ++k) { vals[k] = expf(vals[k] - mx); sum += vals[k]; }
        const float inv = 1.f / sum;
        #pragma unroll
        for (int k = 0; k < L_; ++k) sS2[g][q][k] = vals[k]*inv;
    }
    __syncthreads();

    // w2 mix; write attn_ret[q, bn*H+g, k]
    for (int task = tid; task < H_*L_*L_; task += 192) {
        const int g = task / (L_*L_);
        const int r = task - g*(L_*L_);
        const int q = r / L_;
        const int k = r - q*L_;
        float a = 0.f;
        #pragma unroll
        for (int h = 0; h < H_; ++h) a += sS2[h][q][k] * sW2[h*H_ + g];
        sS[g][q][k] = a;   // sS is dead after softmax phase (barrier-protected)
        attn_out[(size_t)q*((size_t)BNH_*L_) + ((size_t)bn*H_ + g)*L_ + k] = a;
    }
    __syncthreads();

    // context: sum_k attn * (V + relV) -> ctx row (bn*L+q), channel c=h*16+d
    for (int task = tid; task < L_*D_; task += 192) {
        const int q = task >> 7;
        const int c = task & 127;
        const int h = c >> 4;
        const int d = c & 15;
        float a = 0.f;
        #pragma unroll
        for (int k = 0; k < L_; ++k)
            a += sS[h][q][k] * (sQKV[2][k][c] + sRv[(k - q + 11)*DK_ + d]);
        outm[((size_t)bn*L_ + q)*D_ + c] = a;   // ctx staged in out main region
    }
}

// ---------------------------------------------------------------------------
// BN: per-channel sum / sumsq over all 124800 rows (ctx lives in outm)
// ---------------------------------------------------------------------------
__global__ __launch_bounds__(256)
void bnreduce_kernel(const float* __restrict__ outm, float* __restrict__ stats)
{
    const int tid  = threadIdx.x;
    const int c    = tid & 127;
    const int half = tid >> 7;
    float s = 0.f, s2 = 0.f;
    for (int r = blockIdx.x*2 + half; r < ROWS_; r += gridDim.x*2) {
        float v = outm[(size_t)r*D_ + c];
        s += v; s2 += v*v;
    }
    atomicAdd(&stats[c], s);
    atomicAdd(&stats[c+128], s2);
}

__global__ __launch_bounds__(128)
void bnfinal_kernel(const float* __restrict__ stats,
                    const float* __restrict__ gamma, const float* __restrict__ beta,
                    float* __restrict__ stats2)
{
    const int c = threadIdx.x;
    const float invn = 1.f / (float)ROWS_;
    float mean = stats[c]*invn;
    float var  = stats[c+128]*invn - mean*mean;
    float sc   = rsqrtf(var + 1e-5f) * gamma[c];
    stats2[c]     = sc;
    stats2[c+128] = beta[c] - mean*sc;
}

// ---------------------------------------------------------------------------
// fc: normalize ctx (in outm), GEMM vs Wfc, relu + residual, write back in place
// 16 rows per block, 256 threads
// ---------------------------------------------------------------------------
__global__ __launch_bounds__(256)
void fc_kernel(float* __restrict__ outm, const float* __restrict__ stats2,
               const float* __restrict__ Wfc, const float* __restrict__ resid)
{
    __shared__ float sSS[256];
    __shared__ float sC[16][D_];
    const int tid = threadIdx.x;
    const size_t row0 = (size_t)blockIdx.x * 16;

    sSS[tid] = stats2[tid];
    __syncthreads();
    for (int idx = tid; idx < 16*D_; idx += 256) {
        const int r = idx >> 7, c = idx & 127;
        float v = outm[(row0 + r)*D_ + c];
        sC[r][c] = v*sSS[c] + sSS[128+c];
    }
    __syncthreads();

    const int oc = (tid & 63) * 2;
    const int r0 = (tid >> 6) * 4;
    float acc[4][2];
    #pragma unroll
    for (int r = 0; r < 4; ++r) { acc[r][0] = 0.f; acc[r][1] = 0.f; }
    const float* W = Wfc + oc;
    for (int i = 0; i < D_; i += 4) {
        float2 w0 = *(const float2*)&W[(i+0)*D_];
        float2 w1 = *(const float2*)&W[(i+1)*D_];
        float2 w2 = *(const float2*)&W[(i+2)*D_];
        float2 w3 = *(const float2*)&W[(i+3)*D_];
        #pragma unroll
        for (int r = 0; r < 4; ++r) {
            float4 x = *(const float4*)&sC[r0+r][i];
            acc[r][0] += x.x*w0.x + x.y*w1.x + x.z*w2.x + x.w*w3.x;
            acc[r][1] += x.x*w0.y + x.y*w1.y + x.z*w2.y + x.w*w3.y;
        }
    }
    #pragma unroll
    for (int r = 0; r < 4; ++r) {
        const size_t a = (row0 + r0 + r)*D_ + oc;
        outm[a]   = fmaxf(acc[r][0], 0.f) + resid[a];
        outm[a+1] = fmaxf(acc[r][1], 0.f) + resid[a+1];
    }
}

// ---------------------------------------------------------------------------
extern "C" void kernel_launch(void* const* d_in, const int* in_sizes, int n_in,
                              void* d_out, int out_size, void* d_ws, size_t ws_size,
                              hipStream_t stream)
{
    const float* xq   = (const float*)d_in[0];
    const float* xk   = (const float*)d_in[1];
    const float* xv   = (const float*)d_in[2];
    const float* wqv  = (const float*)d_in[3];
    const float* wqg  = (const float*)d_in[4];
    const float* wkv  = (const float*)d_in[5];
    const float* wkg  = (const float*)d_in[6];
    const float* wvv  = (const float*)d_in[7];
    const float* wvg  = (const float*)d_in[8];
    const float* fcv  = (const float*)d_in[9];
    const float* fcg  = (const float*)d_in[10];
    const float* relk = (const float*)d_in[11];
    const float* relv = (const float*)d_in[12];
    const float* w1   = (const float*)d_in[13];
    const float* w2   = (const float*)d_in[14];
    const float* gam  = (const float*)d_in[15];
    const float* bet  = (const float*)d_in[16];

    // ws layout: Wt (4*128*128 f32) | stats (256 f32) | stats2 (256 f32)
    float* Wt     = (float*)d_ws;
    float* stats  = Wt + 4*D_*D_;
    float* stats2 = stats + 256;

    float* outm     = (float*)d_out;          // main output; temporarily holds ctx
    float* attn_out = outm + OUT_MAIN_;

    prep_kernel<<<4*D_ + 1, 64, 0, stream>>>(wqv,wqg, wkv,wkg, wvv,wvg, fcv,fcg,
                                             Wt, stats);
    attn_kernel<<<BN_, 192, 0, stream>>>(xq, xk, xv, relk, relv, w1, w2,
                                         Wt, outm, attn_out);
    bnreduce_kernel<<<512, 256, 0, stream>>>(outm, stats);
    bnfinal_kernel<<<1, 128, 0, stream>>>(stats, gam, bet, stats2);
    fc_kernel<<<ROWS_/16, 256, 0, stream>>>(outm, stats2, Wt + 3*D_*D_, xv);
}

// Round 3
// 489.800 us; speedup vs baseline: 1.5088x; 1.5088x over previous
//
#include <hip/hip_runtime.h>
#include <math.h>

#define B_   32
#define N_   325
#define L_   12
#define D_   128
#define H_   8
#define DK_  16
#define BN_  (B_*N_)        // 10400
#define ROWS_ (BN_*L_)      // 124800
#define TAB_ 23             // 2*MAX_REL+1
#define BNH_ (BN_*H_)       // 83200
#define OUT_MAIN_ ((size_t)ROWS_ * D_)   // 15,974,400 floats

#define XS_  136            // bf16 row stride for staged X (pad 128+8 -> 2-way only)
#define QS_  132            // fp32 row stride for sQ/sV
#define RS_  17             // fp32 row stride for rel tables
#define KTS_ 13             // k-stride pad for transposed K

typedef short v8s __attribute__((ext_vector_type(8)));
typedef float v4f __attribute__((ext_vector_type(4)));

__device__ __forceinline__ unsigned short f2bf_bits(float f) {
    unsigned int u = __float_as_uint(f);
    unsigned int r = (u + 0x7fffu + ((u >> 16) & 1u)) >> 16;
    return (unsigned short)r;
}

// ---------------------------------------------------------------------------
// prep: weight-norm all 4 matrices -> bf16 weights pre-swizzled into the
// MFMA B-fragment order: ushort offset =
//   ((n>>4)*4 + (k>>5))*512 + ((k>>3)&3)*128 + (n&15)*8 + (k&7)
// (frag = [N-tile][K-chunk]; within: lane = quad*16 + n15 holds B[k][n], 8 k's)
// extra block zeroes the BN accumulators (ws is poisoned 0xAA each launch)
// ---------------------------------------------------------------------------
__global__ __launch_bounds__(64)
void prep_kernel(const float* __restrict__ wqv, const float* __restrict__ wqg,
                 const float* __restrict__ wkv, const float* __restrict__ wkg,
                 const float* __restrict__ wvv, const float* __restrict__ wvg,
                 const float* __restrict__ fcv, const float* __restrict__ fcg,
                 unsigned short* __restrict__ Wb, float* __restrict__ stats)
{
    const int b = blockIdx.x, t = threadIdx.x;
    if (b == 4*D_) {
        for (int j = t; j < 256; j += 64) stats[j] = 0.f;
        return;
    }
    const int m = b >> 7, o = b & 127;
    const float* v; const float* g;
    if      (m == 0) { v = wqv; g = wqg; }
    else if (m == 1) { v = wkv; g = wkg; }
    else if (m == 2) { v = wvv; g = wvg; }
    else             { v = fcv; g = fcg; }
    float x0 = v[o*D_ + t];
    float x1 = v[o*D_ + t + 64];
    float ss = x0*x0 + x1*x1;
    #pragma unroll
    for (int off = 32; off > 0; off >>= 1) ss += __shfl_down(ss, off, 64);
    ss = __shfl(ss, 0, 64);
    const float scale = g[o] / sqrtf(ss);
    unsigned short* W = Wb + m*(D_*D_);
    {
        int k = t;
        int off = ((o>>4)*4 + (k>>5))*512 + ((k>>3)&3)*128 + (o&15)*8 + (k&7);
        W[off] = f2bf_bits(x0*scale);
        k = t + 64;
        off = ((o>>4)*4 + (k>>5))*512 + ((k>>3)&3)*128 + (o&15)*8 + (k&7);
        W[off] = f2bf_bits(x1*scale);
    }
}

// ---------------------------------------------------------------------------
// attention: one block per (b,n). 192 threads = 3 waves (one per Q/K/V matrix).
// Projection via mfma_f32_16x16x32_bf16; rest scalar.
// ---------------------------------------------------------------------------
__global__ __launch_bounds__(192, 3)
void attn_kernel(const float* __restrict__ xq, const float* __restrict__ xk,
                 const float* __restrict__ xv,
                 const float* __restrict__ relk, const float* __restrict__ relv,
                 const float* __restrict__ w1g, const float* __restrict__ w2g,
                 const unsigned short* __restrict__ Wb,
                 float* __restrict__ outm, float* __restrict__ attn_out)
{
    // smem region: staged bf16 X during projection; sS/sS2 afterwards
    __shared__ __align__(16) char smem[3*16*XS_*2];      // 13056 B >= 9216 B
    __shared__ __align__(16) float sQ[L_][QS_];
    __shared__ __align__(16) float sV[L_][QS_];
    __shared__ float sKt[H_*DK_*KTS_];                   // [h][d][k] stride 13
    __shared__ float sRk[TAB_*RS_];
    __shared__ float sRv[TAB_*RS_];
    __shared__ float sW1[H_*H_];
    __shared__ float sW2[H_*H_];

    unsigned short (*sXb)[16][XS_] =
        reinterpret_cast<unsigned short (*)[16][XS_]>(smem);
    float* pS  = (float*)smem;        // [H][L][L] flat = 1152 floats
    float* pS2 = pS + H_*L_*L_;

    const int tid = threadIdx.x;
    const int bn  = blockIdx.x;
    const size_t base = (size_t)bn * (L_*D_);

    // ---- stage inputs -> bf16 LDS (rows 12..15 zero) ----
    #pragma unroll
    for (int mat = 0; mat < 3; ++mat) {
        const float* src = (mat == 0) ? xq : ((mat == 1) ? xk : xv);
        const float4* s4 = (const float4*)(src + base);
        for (int idx = tid; idx < L_*D_/4; idx += 192) {   // 384 float4
            const int row = idx >> 5;
            const int c4  = (idx & 31) * 4;
            float4 v = s4[idx];
            ushort4 u;
            u.x = f2bf_bits(v.x); u.y = f2bf_bits(v.y);
            u.z = f2bf_bits(v.z); u.w = f2bf_bits(v.w);
            *(ushort4*)&sXb[mat][row][c4] = u;
        }
    }
    for (int idx = tid; idx < 3*272; idx += 192) {   // zero rows 12..15 (uints)
        const int mat = idx / 272, o = idx - mat*272;
        ((unsigned int*)&sXb[mat][12][0])[o] = 0u;
    }
    for (int idx = tid; idx < TAB_*DK_; idx += 192) {
        const int r = idx >> 4, c = idx & 15;
        sRk[r*RS_ + c] = relk[idx];
        sRv[r*RS_ + c] = relv[idx];
    }
    if (tid < H_*H_) { sW1[tid] = w1g[tid]; sW2[tid] = w2g[tid]; }
    __syncthreads();

    // ---- QKV projection via MFMA: wave `mat`, lane holds A[row=c15][k] ----
    {
        const int mat  = tid / 64;        // wave-uniform
        const int lane = tid & 63;
        const int quad = lane >> 4;
        const int c15  = lane & 15;
        v8s a[4];
        #pragma unroll
        for (int kk = 0; kk < 4; ++kk)
            a[kk] = *(const v8s*)&sXb[mat][c15][kk*32 + quad*8];
        const v8s* WB = (const v8s*)(Wb + mat*(D_*D_));
        const int token0 = quad*4;
        #pragma unroll
        for (int tile = 0; tile < 8; ++tile) {
            v4f acc = {0.f, 0.f, 0.f, 0.f};
            #pragma unroll
            for (int kk = 0; kk < 4; ++kk) {
                v8s bfrag = WB[(tile*4 + kk)*64 + lane];
                acc = __builtin_amdgcn_mfma_f32_16x16x32_bf16(a[kk], bfrag, acc, 0, 0, 0);
            }
            if (mat == 1) {              // K -> transposed per head: sKt[h][d][k]
                #pragma unroll
                for (int r = 0; r < 4; ++r)
                    if (token0 + r < L_)
                        sKt[tile*(DK_*KTS_) + c15*KTS_ + token0 + r] = acc[r];
            } else {
                float (*dst)[QS_] = (mat == 0) ? sQ : sV;
                #pragma unroll
                for (int r = 0; r < 4; ++r)
                    if (token0 + r < L_)
                        dst[token0 + r][tile*16 + c15] = acc[r];
            }
        }
    }
    __syncthreads();

    // ---- scores: s1+s2 = sum_d Q*(K + relK), scale 0.25 ----
    for (int task = tid; task < H_*L_*L_; task += 192) {
        const int h = task / (L_*L_);
        const int r = task - h*(L_*L_);
        const int q = r / L_;
        const int k = r - q*L_;
        const float* Qp = &sQ[q][h*DK_];
        const float* Kp = &sKt[h*(DK_*KTS_) + k];
        const float* Rp = &sRk[(k - q + 11)*RS_];
        float s = 0.f;
        #pragma unroll
        for (int d = 0; d < DK_; ++d) s += Qp[d] * (Kp[d*KTS_] + Rp[d]);
        pS[task] = s * 0.25f;
    }
    __syncthreads();

    // ---- w1 mix -> leaky relu -> softmax over k ----
    if (tid < H_*L_) {
        const int g = tid / L_;
        const int q = tid - g*L_;
        float vals[L_];
        float mx = -1e30f;
        #pragma unroll
        for (int k = 0; k < L_; ++k) {
            float a = 0.f;
            #pragma unroll
            for (int h = 0; h < H_; ++h) a += pS[h*(L_*L_) + q*L_ + k] * sW1[h*H_ + g];
            a = (a >= 0.f) ? a : 0.2f*a;
            vals[k] = a;
            mx = fmaxf(mx, a);
        }
        float sum = 0.f;
        #pragma unroll
        for (int k = 0; k < L_; ++k) { vals[k] = expf(vals[k] - mx); sum += vals[k]; }
        const float inv = 1.f / sum;
        #pragma unroll
        for (int k = 0; k < L_; ++k) pS2[g*(L_*L_) + q*L_ + k] = vals[k]*inv;
    }
    __syncthreads();

    // ---- w2 mix; write attn_ret[q, bn*H+g, k] ----
    for (int task = tid; task < H_*L_*L_; task += 192) {
        const int g = task / (L_*L_);
        const int r = task - g*(L_*L_);
        const int q = r / L_;
        const int k = r - q*L_;
        float a = 0.f;
        #pragma unroll
        for (int h = 0; h < H_; ++h) a += pS2[h*(L_*L_) + q*L_ + k] * sW2[h*H_ + g];
        pS[task] = a;
        attn_out[(size_t)q*((size_t)BNH_*L_) + ((size_t)bn*H_ + g)*L_ + k] = a;
    }
    __syncthreads();

    // ---- context: sum_k attn * (V + relV) -> ctx row (bn*L+q) ----
    for (int task = tid; task < L_*D_; task += 192) {
        const int q = task >> 7;
        const int c = task & 127;
        const int h = c >> 4;
        const int d = c & 15;
        float a = 0.f;
        #pragma unroll
        for (int k = 0; k < L_; ++k)
            a += pS[h*(L_*L_) + q*L_ + k] * (sV[k][c] + sRv[(k - q + 11)*RS_ + d]);
        outm[((size_t)bn*L_ + q)*D_ + c] = a;
    }
}

// ---------------------------------------------------------------------------
// BN: per-channel sum / sumsq over all 124800 rows (ctx lives in outm)
// ---------------------------------------------------------------------------
__global__ __launch_bounds__(256)
void bnreduce_kernel(const float* __restrict__ outm, float* __restrict__ stats)
{
    const int tid  = threadIdx.x;
    const int c    = tid & 127;
    const int half = tid >> 7;
    float s = 0.f, s2 = 0.f;
    for (int r = blockIdx.x*2 + half; r < ROWS_; r += gridDim.x*2) {
        float v = outm[(size_t)r*D_ + c];
        s += v; s2 += v*v;
    }
    atomicAdd(&stats[c], s);
    atomicAdd(&stats[c+128], s2);
}

__global__ __launch_bounds__(128)
void bnfinal_kernel(const float* __restrict__ stats,
                    const float* __restrict__ gamma, const float* __restrict__ beta,
                    float* __restrict__ stats2)
{
    const int c = threadIdx.x;
    const float invn = 1.f / (float)ROWS_;
    float mean = stats[c]*invn;
    float var  = stats[c+128]*invn - mean*mean;
    float sc   = rsqrtf(var + 1e-5f) * gamma[c];
    stats2[c]     = sc;
    stats2[c+128] = beta[c] - mean*sc;
}

// ---------------------------------------------------------------------------
// fc: normalize ctx (in outm) -> bf16 LDS, MFMA vs Wfc, relu+residual in place.
// 16 rows per block, 256 threads = 4 waves; wave w does N-tiles {2w, 2w+1}.
// ---------------------------------------------------------------------------
__global__ __launch_bounds__(256, 4)
void fc_kernel(float* __restrict__ outm, const float* __restrict__ stats2,
               const unsigned short* __restrict__ Wfc,
               const float* __restrict__ resid)
{
    __shared__ float sSS[256];
    __shared__ __align__(16) unsigned short sC[16][XS_];
    const int tid = threadIdx.x;
    const size_t row0 = (size_t)blockIdx.x * 16;

    sSS[tid] = stats2[tid];
    __syncthreads();
    for (int idx = tid; idx < 16*D_/4; idx += 256) {   // 512 float4
        const int r  = idx >> 5;
        const int c4 = (idx & 31) * 4;
        float4 v = *(const float4*)&outm[(row0 + r)*D_ + c4];
        ushort4 u;
        u.x = f2bf_bits(v.x*sSS[c4+0] + sSS[128+c4+0]);
        u.y = f2bf_bits(v.y*sSS[c4+1] + sSS[128+c4+1]);
        u.z = f2bf_bits(v.z*sSS[c4+2] + sSS[128+c4+2]);
        u.w = f2bf_bits(v.w*sSS[c4+3] + sSS[128+c4+3]);
        *(ushort4*)&sC[r][c4] = u;
    }
    __syncthreads();

    const int wave = tid >> 6;
    const int lane = tid & 63;
    const int quad = lane >> 4;
    const int c15  = lane & 15;
    v8s a[4];
    #pragma unroll
    for (int kk = 0; kk < 4; ++kk)
        a[kk] = *(const v8s*)&sC[c15][kk*32 + quad*8];
    const v8s* WB = (const v8s*)Wfc;
    #pragma unroll
    for (int tt = 0; tt < 2; ++tt) {
        const int tile = wave*2 + tt;
        v4f acc = {0.f, 0.f, 0.f, 0.f};
        #pragma unroll
        for (int kk = 0; kk < 4; ++kk) {
            v8s bfrag = WB[(tile*4 + kk)*64 + lane];
            acc = __builtin_amdgcn_mfma_f32_16x16x32_bf16(a[kk], bfrag, acc, 0, 0, 0);
        }
        #pragma unroll
        for (int r = 0; r < 4; ++r) {
            const size_t aidx = (row0 + quad*4 + r)*D_ + tile*16 + c15;
            outm[aidx] = fmaxf(acc[r], 0.f) + resid[aidx];
        }
    }
}

// ---------------------------------------------------------------------------
extern "C" void kernel_launch(void* const* d_in, const int* in_sizes, int n_in,
                              void* d_out, int out_size, void* d_ws, size_t ws_size,
                              hipStream_t stream)
{
    const float* xq   = (const float*)d_in[0];
    const float* xk   = (const float*)d_in[1];
    const float* xv   = (const float*)d_in[2];
    const float* wqv  = (const float*)d_in[3];
    const float* wqg  = (const float*)d_in[4];
    const float* wkv  = (const float*)d_in[5];
    const float* wkg  = (const float*)d_in[6];
    const float* wvv  = (const float*)d_in[7];
    const float* wvg  = (const float*)d_in[8];
    const float* fcv  = (const float*)d_in[9];
    const float* fcg  = (const float*)d_in[10];
    const float* relk = (const float*)d_in[11];
    const float* relv = (const float*)d_in[12];
    const float* w1   = (const float*)d_in[13];
    const float* w2   = (const float*)d_in[14];
    const float* gam  = (const float*)d_in[15];
    const float* bet  = (const float*)d_in[16];

    // ws layout: Wb bf16 swizzled (4*128*128 ushort = 128 KB) | stats | stats2
    unsigned short* Wb = (unsigned short*)d_ws;
    float* stats  = (float*)((char*)d_ws + 4*D_*D_*sizeof(unsigned short));
    float* stats2 = stats + 256;

    float* outm     = (float*)d_out;          // main output; temporarily holds ctx
    float* attn_out = outm + OUT_MAIN_;

    prep_kernel<<<4*D_ + 1, 64, 0, stream>>>(wqv,wqg, wkv,wkg, wvv,wvg, fcv,fcg,
                                             Wb, stats);
    attn_kernel<<<BN_, 192, 0, stream>>>(xq, xk, xv, relk, relv, w1, w2,
                                         Wb, outm, attn_out);
    bnreduce_kernel<<<512, 256, 0, stream>>>(outm, stats);
    bnfinal_kernel<<<1, 128, 0, stream>>>(stats, gam, bet, stats2);
    fc_kernel<<<ROWS_/16, 256, 0, stream>>>(outm, stats2, Wb + 3*D_*D_, xv);
}